// Round 11
// baseline (1543.153 us; speedup 1.0000x reference)
//
#include <hip/hip_runtime.h>

typedef unsigned short u16;
typedef unsigned int   u32;
typedef __attribute__((ext_vector_type(2))) u16 u16x2;
typedef __attribute__((ext_vector_type(4))) u16 u16x4;
typedef __attribute__((ext_vector_type(8))) u16 u16x8;
typedef __attribute__((ext_vector_type(8))) __bf16 bf16x8;
typedef __attribute__((ext_vector_type(4))) float f32x4;

#define HIDDEN 3072
#define LTOT 1280
#define BATCH 2
#define NROWS (BATCH*LTOT)      // 2560
#define HEADS 24
#define HD 128
#define N1 21504                // 3*HIDDEN + 12288
#define QKVW 9216
#define MLPW 12288
#define A2W 15360               // HIDDEN + MLPW
#define EPSF 1e-6f

__device__ __forceinline__ float b2f(u16 u) {
  union { u32 i; float f; } v; v.i = ((u32)u) << 16; return v.f;
}
__device__ __forceinline__ u16 f2b(float f) {
  union { float f; u32 i; } v; v.f = f;
  u32 r = (v.i + 0x7FFFu + ((v.i >> 16) & 1u)) >> 16;
  return (u16)r;
}
// dual-dtype scalar load: flag=1 -> bf16, flag=0 -> f32
__device__ __forceinline__ float lde(const void* p, size_t i, int f) {
  return f ? b2f(((const u16*)p)[i]) : ((const float*)p)[i];
}
__device__ __forceinline__ void gload16(const void* g, void* l) {
  __builtin_amdgcn_global_load_lds((const __attribute__((address_space(1))) void*)g,
                                   (__attribute__((address_space(3))) void*)l, 16, 0, 0);
}
__device__ __forceinline__ bf16x8 ldf(const u16* p) {
  return __builtin_bit_cast(bf16x8, *(const u16x8*)p);
}
__device__ __forceinline__ float gelu_tanh(float x) {
  float u = 0.7978845608028654f * (x + 0.044715f * x * x * x);
  float e = __expf(2.0f * u);
  float th = 1.0f - 2.0f / (e + 1.0f);
  return 0.5f * x * (1.0f + th);
}

// ---------- dtype detect ----------
__global__ void detect_kernel(const u16* __restrict__ fcos, int* __restrict__ dflag) {
  if (threadIdx.x == 0 && blockIdx.x == 0) *dflag = (fcos[0] == 0x3F80) ? 1 : 0;
}

// ---------- small prep kernels ----------
__global__ void silu_kernel(const void* __restrict__ vec, float* __restrict__ sv,
                            const int* __restrict__ dflag) {
  int flag = *dflag;
  int i = blockIdx.x * 256 + threadIdx.x;
  if (i < BATCH * HIDDEN) { float x = lde(vec, i, flag); sv[i] = x / (1.0f + __expf(-x)); }
}

__global__ void modmul(const void* __restrict__ wmod, const float* __restrict__ sv,
                       float* __restrict__ modp, const int* __restrict__ dflag) {
  int flag = *dflag;
  int j = blockIdx.x * 256 + threadIdx.x;
  int kc = blockIdx.y;
  float a = 0.f, c = 0.f;
  int k0 = kc * 384;
  for (int k = k0; k < k0 + 384; ++k) {
    float w = lde(wmod, (size_t)k * QKVW + j, flag);
    a += sv[k] * w; c += sv[HIDDEN + k] * w;
  }
  modp[(size_t)kc * 2 * QKVW + j] = a;
  modp[(size_t)kc * 2 * QKVW + QKVW + j] = c;
}

__global__ void modred(const float* __restrict__ modp, const void* __restrict__ bmod,
                       float* __restrict__ mod, const int* __restrict__ dflag) {
  int flag = *dflag;
  int j = blockIdx.x * 256 + threadIdx.x;
  float bv = lde(bmod, j, flag);
  float a = bv, c = bv;
#pragma unroll
  for (int kc = 0; kc < 8; ++kc) {
    a += modp[(size_t)kc * 2 * QKVW + j];
    c += modp[(size_t)kc * 2 * QKVW + QKVW + j];
  }
  mod[j] = a; mod[QKVW + j] = c;
}

__global__ __launch_bounds__(256) void ln_mod_kernel(const void* __restrict__ x,
                                                     const float* __restrict__ mod,
                                                     u16* __restrict__ xmod,
                                                     const int* __restrict__ dflag) {
  int flag = *dflag;
  int row = blockIdx.x;
  int b = row / LTOT;
  int t = threadIdx.x, w = t >> 6, l = t & 63;
  float v[12], sum = 0.0f, sq = 0.0f;
  if (flag) {
    const u16* xr = (const u16*)x + (size_t)row * HIDDEN;
#pragma unroll
    for (int p = 0; p < 3; ++p) {
      u16x4 u = *(const u16x4*)&xr[p * 1024 + t * 4];
#pragma unroll
      for (int i = 0; i < 4; ++i) { float f = b2f(u[i]); v[p * 4 + i] = f; sum += f; sq += f * f; }
    }
  } else {
    const float* xr = (const float*)x + (size_t)row * HIDDEN;
#pragma unroll
    for (int p = 0; p < 3; ++p) {
      f32x4 u = *(const f32x4*)&xr[p * 1024 + t * 4];
#pragma unroll
      for (int i = 0; i < 4; ++i) { float f = u[i]; v[p * 4 + i] = f; sum += f; sq += f * f; }
    }
  }
#pragma unroll
  for (int off = 1; off < 64; off <<= 1) { sum += __shfl_xor(sum, off, 64); sq += __shfl_xor(sq, off, 64); }
  __shared__ float red[2][4];
  if (l == 0) { red[0][w] = sum; red[1][w] = sq; }
  __syncthreads();
  sum = red[0][0] + red[0][1] + red[0][2] + red[0][3];
  sq  = red[1][0] + red[1][1] + red[1][2] + red[1][3];
  float mu = sum / (float)HIDDEN;
  float var = sq / (float)HIDDEN - mu * mu;
  float rs = rsqrtf(var + EPSF);
  const float* mb = mod + (size_t)b * QKVW;
#pragma unroll
  for (int p = 0; p < 3; ++p) {
    u16x4 o;
#pragma unroll
    for (int i = 0; i < 4; ++i) {
      int col = p * 1024 + t * 4 + i;
      float y = (v[p * 4 + i] - mu) * rs;
      o[i] = f2b(y * (1.0f + mb[HIDDEN + col]) + mb[col]);
    }
    *(u16x4*)&xmod[(size_t)row * HIDDEN + p * 1024 + t * 4] = o;
  }
}

// ---------- transpose with dtype convert ----------
__global__ void transpose_cvt(const void* __restrict__ in, u16* __restrict__ out,
                              int R, int C, const int* __restrict__ dflag) {
  int flag = *dflag;
  __shared__ u16 tile[32][33];
  int bx = blockIdx.x * 32, by = blockIdx.y * 32;
  int tx = threadIdx.x & 31, ty = threadIdx.x >> 5;
#pragma unroll
  for (int i = 0; i < 32; i += 8)
    tile[ty + i][tx] = f2b(lde(in, (size_t)(by + ty + i) * C + bx + tx, flag));
  __syncthreads();
#pragma unroll
  for (int i = 0; i < 32; i += 8) out[(size_t)(bx + ty + i) * R + by + tx] = tile[tx][ty + i];
}

// ---------- transpose bf16 ----------
__global__ void transpose_bf16(const u16* __restrict__ in, u16* __restrict__ out,
                               int R, int C, size_t ibs, size_t obs) {
  in  += (size_t)blockIdx.z * ibs;
  out += (size_t)blockIdx.z * obs;
  __shared__ u16 tile[32][33];
  int bx = blockIdx.x * 32, by = blockIdx.y * 32;
  int tx = threadIdx.x & 31, ty = threadIdx.x >> 5;
#pragma unroll
  for (int i = 0; i < 32; i += 8) tile[ty + i][tx] = in[(size_t)(by + ty + i) * C + bx + tx];
  __syncthreads();
#pragma unroll
  for (int i = 0; i < 32; i += 8) out[(size_t)(bx + ty + i) * R + by + tx] = tile[tx][ty + i];
}

// ---------- GEMM1: 256x256 tile, faithful m201 8-phase (4 phases/K-tile) ----------
// Per phase: {ds_read subtile -> stage ONE 2-gload slice -> [vmcnt] -> s_barrier ->
//             lgkmcnt(0)+sched_barrier -> setprio(1) 16 MFMA setprio(0) -> s_barrier}.
// Slice order per tile: A0,B0,A1,B1 (2 gloads each). vmcnt(4) at PH1 (confirms A1,B1 of
// tile t) and PH3 (confirms A0,B0 of tile t+1); 4-8 loads always in flight; vmcnt(0)
// only at last tile's PH1. Zero-conflict chunk-XOR swizzle (proven r5-r10).
__global__ __launch_bounds__(512, 2) void gemm1_8ph(
    const u16* __restrict__ A, const u16* __restrict__ Bt,
    const void* __restrict__ bias,
    u16* __restrict__ Qb, u16* __restrict__ Kb, u16* __restrict__ Vb,
    u16* __restrict__ A2, const int* __restrict__ dflag) {
  __shared__ u16 As[2][2][256][32];
  __shared__ u16 Bs[2][2][256][32];
  constexpr int K = HIDDEN;
  constexpr int NT = K / 64;           // 48
  const int tid = threadIdx.x;
  const int l = tid & 63, w = tid >> 6;
  const int wr = w >> 2, wc = w & 3;   // 2 x 4 wave grid; per-wave out 128x64
  const int lr = l & 15, g = l >> 4;
  const int lk_sw = (g ^ ((lr >> 1) & 3)) * 8;   // swizzled fragment k-offset (u16)

  // XCD-aware block swizzle: 840 = 8 * 105 (bijective)
  const int orig = blockIdx.x;
  const int wgid = (orig & 7) * 105 + (orig >> 3);
  const int my = wgid / 84, nx = wgid - my * 84;
  const int bm = my * 256, bn = nx * 256;

  // staging: LDS linear (base + lane*16); global source pre-swizzled (rule #21)
  const int row_s = tid >> 2, chunk = tid & 3;
  const int c_log = chunk ^ ((row_s >> 1) & 3);
  const u16* pa = A  + (size_t)(bm + row_s) * K + c_log * 8;
  const u16* pb = Bt + (size_t)(bn + row_s) * K + c_log * 8;

  auto stage_a = [&](int buf, int kk, int t) {
    const u16* sa = pa + kk * 32 + t * 64;
    u16* la = &As[buf][kk][row_s][chunk * 8];
    gload16(sa,                   la);
    gload16(sa + (size_t)128 * K, la + 128 * 32);
  };
  auto stage_b = [&](int buf, int kk, int t) {
    const u16* sb = pb + kk * 32 + t * 64;
    u16* lb = &Bs[buf][kk][row_s][chunk * 8];
    gload16(sb,                   lb);
    gload16(sb + (size_t)128 * K, lb + 128 * 32);
  };

  f32x4 acc[8][4] = {};

  // prologue: all 4 slices of tile 0; confirm slice-pair 0
  stage_a(0, 0, 0); stage_b(0, 0, 0); stage_a(0, 1, 0); stage_b(0, 1, 0);
  asm volatile("s_waitcnt vmcnt(4)" ::: "memory");
  __builtin_amdgcn_s_barrier();

  bf16x8 af[4], bfr[4];
  for (int t = 0; t < NT; ++t) {
    const int b = t & 1;
    const bool pre = (t + 1 < NT);

    // ---- PH0: rows 0-3, kk0
#pragma unroll
    for (int fc = 0; fc < 4; ++fc) bfr[fc] = ldf(&Bs[b][0][wc * 64 + fc * 16 + lr][lk_sw]);
#pragma unroll
    for (int j = 0; j < 4; ++j) af[j] = ldf(&As[b][0][wr * 128 + j * 16 + lr][lk_sw]);
    if (pre) stage_a(b ^ 1, 0, t + 1);
    __builtin_amdgcn_s_barrier();
    asm volatile("s_waitcnt lgkmcnt(0)" ::: "memory");
    __builtin_amdgcn_sched_barrier(0);
    __builtin_amdgcn_s_setprio(1);
#pragma unroll
    for (int j = 0; j < 4; ++j)
#pragma unroll
      for (int fc = 0; fc < 4; ++fc)
        acc[j][fc] = __builtin_amdgcn_mfma_f32_16x16x32_bf16(af[j], bfr[fc], acc[j][fc], 0, 0, 0);
    __builtin_amdgcn_s_setprio(0);
    __builtin_amdgcn_s_barrier();

    // ---- PH1: rows 4-7, kk0 (bfr reused)
#pragma unroll
    for (int j = 0; j < 4; ++j) af[j] = ldf(&As[b][0][wr * 128 + (4 + j) * 16 + lr][lk_sw]);
    if (pre) stage_b(b ^ 1, 0, t + 1);
    if (pre) { asm volatile("s_waitcnt vmcnt(4)" ::: "memory"); }   // lands A1(t),B1(t)
    else     { asm volatile("s_waitcnt vmcnt(0)" ::: "memory"); }
    __builtin_amdgcn_s_barrier();
    asm volatile("s_waitcnt lgkmcnt(0)" ::: "memory");
    __builtin_amdgcn_sched_barrier(0);
    __builtin_amdgcn_s_setprio(1);
#pragma unroll
    for (int j = 0; j < 4; ++j)
#pragma unroll
      for (int fc = 0; fc < 4; ++fc)
        acc[4 + j][fc] = __builtin_amdgcn_mfma_f32_16x16x32_bf16(af[j], bfr[fc], acc[4 + j][fc], 0, 0, 0);
    __builtin_amdgcn_s_setprio(0);
    __builtin_amdgcn_s_barrier();

    // ---- PH2: rows 0-3, kk1
#pragma unroll
    for (int fc = 0; fc < 4; ++fc) bfr[fc] = ldf(&Bs[b][1][wc * 64 + fc * 16 + lr][lk_sw]);
#pragma unroll
    for (int j = 0; j < 4; ++j) af[j] = ldf(&As[b][1][wr * 128 + j * 16 + lr][lk_sw]);
    if (pre) stage_a(b ^ 1, 1, t + 1);
    __builtin_amdgcn_s_barrier();
    asm volatile("s_waitcnt lgkmcnt(0)" ::: "memory");
    __builtin_amdgcn_sched_barrier(0);
    __builtin_amdgcn_s_setprio(1);
#pragma unroll
    for (int j = 0; j < 4; ++j)
#pragma unroll
      for (int fc = 0; fc < 4; ++fc)
        acc[j][fc] = __builtin_amdgcn_mfma_f32_16x16x32_bf16(af[j], bfr[fc], acc[j][fc], 0, 0, 0);
    __builtin_amdgcn_s_setprio(0);
    __builtin_amdgcn_s_barrier();

    // ---- PH3: rows 4-7, kk1
#pragma unroll
    for (int j = 0; j < 4; ++j) af[j] = ldf(&As[b][1][wr * 128 + (4 + j) * 16 + lr][lk_sw]);
    if (pre) {
      stage_b(b ^ 1, 1, t + 1);
      asm volatile("s_waitcnt vmcnt(4)" ::: "memory");   // lands A0(t+1),B0(t+1)
    }
    __builtin_amdgcn_s_barrier();
    asm volatile("s_waitcnt lgkmcnt(0)" ::: "memory");
    __builtin_amdgcn_sched_barrier(0);
    __builtin_amdgcn_s_setprio(1);
#pragma unroll
    for (int j = 0; j < 4; ++j)
#pragma unroll
      for (int fc = 0; fc < 4; ++fc)
        acc[4 + j][fc] = __builtin_amdgcn_mfma_f32_16x16x32_bf16(af[j], bfr[fc], acc[4 + j][fc], 0, 0, 0);
    __builtin_amdgcn_s_setprio(0);
    __builtin_amdgcn_s_barrier();
  }

  // epilogue (unchanged, proven)
  const int flag = *dflag;
#pragma unroll
  for (int fr = 0; fr < 8; ++fr) {
#pragma unroll
    for (int fc = 0; fc < 4; ++fc) {
      int colg = bn + wc * 64 + fc * 16 + lr;
      float bv = lde(bias, colg, flag);
#pragma unroll
      for (int r = 0; r < 4; ++r) {
        int rowg = bm + wr * 128 + fr * 16 + g * 4 + r;
        float v = acc[fr][fc][r] + bv;
        if (colg < QKVW) {
          int which = colg / HIDDEN;
          int hd = colg - which * HIDDEN;
          int h = hd >> 7, d = hd & 127;
          int b2 = rowg / LTOT, pos = rowg - b2 * LTOT;
          u16* dst = (which == 0) ? Qb : ((which == 1) ? Kb : Vb);
          dst[(((size_t)(b2 * HEADS + h)) * LTOT + pos) * HD + d] = f2b(v);
        } else {
          A2[(size_t)rowg * A2W + HIDDEN + (colg - QKVW)] = f2b(gelu_tanh(v));
        }
      }
    }
  }
}

// ---------- GEMM (m97 structure, kept for GEMM2) ----------
template <int MODE>
__global__ __launch_bounds__(256) void gemm_bt(
    const u16* __restrict__ A, const u16* __restrict__ Bt, int K,
    const void* __restrict__ bias,
    u16* __restrict__ out0, u16* __restrict__ out1, u16* __restrict__ out2,
    u16* __restrict__ out3, float* __restrict__ outf,
    const void* __restrict__ xin, const float* __restrict__ mod,
    const int* __restrict__ dflag) {
  __shared__ u16 As[128 * 32];
  __shared__ u16 Bs[128 * 32];
  const int flag = *dflag;
  const int t = threadIdx.x;
  const int bn = blockIdx.x * 128;
  const int bm = blockIdx.y * 128;
  const int w = t >> 6, l = t & 63;
  const int wr = (w >> 1) * 64, wc = (w & 1) * 64;
  const int lr = l & 15, lk = (l >> 4) * 8;
  f32x4 acc[4][4] = {};
  const size_t a_base = (size_t)bm * K;
  const size_t b_base = (size_t)bn * K;
  const int e0 = t * 8, e1 = e0 + 2048;
  const int r0 = e0 >> 5, c0 = e0 & 31;
  const int r1 = e1 >> 5, c1 = e1 & 31;
  const int nk = K / 32;
  for (int kt = 0; kt < nk; ++kt) {
    const int k0 = kt * 32;
    __syncthreads();
    gload16(A + a_base + (size_t)r0 * K + k0 + c0, (u16*)As + e0);
    gload16(A + a_base + (size_t)r1 * K + k0 + c1, (u16*)As + e1);
    gload16(Bt + b_base + (size_t)r0 * K + k0 + c0, (u16*)Bs + e0);
    gload16(Bt + b_base + (size_t)r1 * K + k0 + c1, (u16*)Bs + e1);
    __syncthreads();
    bf16x8 af[4], bfr[4];
#pragma unroll
    for (int i = 0; i < 4; ++i) {
      af[i]  = __builtin_bit_cast(bf16x8, *(const u16x8*)&As[(wr + i * 16 + lr) * 32 + lk]);
      bfr[i] = __builtin_bit_cast(bf16x8, *(const u16x8*)&Bs[(wc + i * 16 + lr) * 32 + lk]);
    }
#pragma unroll
    for (int i = 0; i < 4; ++i)
#pragma unroll
      for (int j = 0; j < 4; ++j)
        acc[i][j] = __builtin_amdgcn_mfma_f32_16x16x32_bf16(af[i], bfr[j], acc[i][j], 0, 0, 0);
  }
#pragma unroll
  for (int i = 0; i < 4; ++i) {
#pragma unroll
    for (int j = 0; j < 4; ++j) {
      int colg = bn + wc + j * 16 + lr;
      float bv = lde(bias, colg, flag);
#pragma unroll
      for (int r = 0; r < 4; ++r) {
        int rowg = bm + wr + i * 16 + (l >> 4) * 4 + r;
        float v = acc[i][j][r] + bv;
        if (MODE == 1) {
          // unused
        } else {
          int b = rowg / LTOT;
          float gg = mod[(size_t)b * QKVW + 2 * HIDDEN + colg];
          float xv = lde(xin, (size_t)rowg * HIDDEN + colg, flag);
          outf[(size_t)rowg * HIDDEN + colg] = xv + v * gg;
        }
      }
    }
  }
}

// ---------- in-place RMS norm + RoPE ----------
__global__ __launch_bounds__(256) void rms_rope(
    u16* __restrict__ Qb, u16* __restrict__ Kb,
    const void* __restrict__ qg, const void* __restrict__ kg,
    const void* __restrict__ fcos, const void* __restrict__ fsin,
    const int* __restrict__ dflag) {
  int flag = *dflag;
  int w = threadIdx.x >> 6, l = threadIdx.x & 63;
  int rid = blockIdx.x * 4 + w;
  int pos = rid % LTOT;
  int d0 = 2 * l;
  size_t off = (size_t)rid * HD + d0;
  u16x2 qu = *(const u16x2*)&Qb[off];
  u16x2 ku = *(const u16x2*)&Kb[off];
  float q0 = b2f(qu[0]), q1 = b2f(qu[1]);
  float k0 = b2f(ku[0]), k1 = b2f(ku[1]);
  float sq = q0 * q0 + q1 * q1, sk = k0 * k0 + k1 * k1;
#pragma unroll
  for (int o = 1; o < 64; o <<= 1) { sq += __shfl_xor(sq, o, 64); sk += __shfl_xor(sk, o, 64); }
  float rq = rsqrtf(sq / 128.0f + EPSF), rk = rsqrtf(sk / 128.0f + EPSF);
  q0 *= rq * lde(qg, d0, flag); q1 *= rq * lde(qg, d0 + 1, flag);
  k0 *= rk * lde(kg, d0, flag); k1 *= rk * lde(kg, d0 + 1, flag);
  if (pos < 1024) {
    float cc = lde(fcos, (size_t)pos * HD + d0, flag);
    float ss = lde(fsin, (size_t)pos * HD + d0, flag);
    float nq0 = q0 * cc - q1 * ss, nq1 = q1 * cc + q0 * ss;
    float nk0 = k0 * cc - k1 * ss, nk1 = k1 * cc + k0 * ss;
    q0 = nq0; q1 = nq1; k0 = nk0; k1 = nk1;
  }
  u16x2 qo; qo[0] = f2b(q0); qo[1] = f2b(q1);
  u16x2 ko; ko[0] = f2b(k0); ko[1] = f2b(k1);
  *(u16x2*)&Qb[off] = qo;
  *(u16x2*)&Kb[off] = ko;
}

// ---------- flash attention (MFMA, proven round 5) ----------
__global__ __launch_bounds__(256) void attn_kernel(
    const u16* __restrict__ Qb, const u16* __restrict__ Kb, const u16* __restrict__ Vt,
    u16* __restrict__ A2) {
  __shared__ u16 Ks[32 * 128];
  __shared__ u16 Vs[128 * 32];
  __shared__ u16 Ps[4][512];
  int t = threadIdx.x, w = t >> 6, l = t & 63;
  int bh = blockIdx.y;
  int q0 = blockIdx.x * 64 + w * 16;
  size_t base = (size_t)bh * LTOT * HD;
  int lr = l & 15, lk = (l >> 4) * 8;
  const float scale = 0.08838834764831845f;

  bf16x8 qf[4];
#pragma unroll
  for (int c = 0; c < 4; ++c)
    qf[c] = __builtin_bit_cast(bf16x8, *(const u16x8*)&Qb[base + (size_t)(q0 + lr) * HD + c * 32 + lk]);

  f32x4 o[8] = {};
  float mrun[4] = {-1e30f, -1e30f, -1e30f, -1e30f};
  float lrun[4] = {0.f, 0.f, 0.f, 0.f};

  const int e0 = t * 8, e1 = e0 + 2048;
  const int vd0 = e0 >> 5, vc0 = e0 & 31;
  const int vd1 = e1 >> 5, vc1 = e1 & 31;

  for (int kt = 0; kt < LTOT / 32; ++kt) {
    __syncthreads();
    gload16(Kb + base + (size_t)kt * 32 * HD + e0, (u16*)Ks + e0);
    gload16(Kb + base + (size_t)kt * 32 * HD + e1, (u16*)Ks + e1);
    gload16(Vt + base + (size_t)vd0 * LTOT + kt * 32 + vc0, (u16*)Vs + e0);
    gload16(Vt + base + (size_t)vd1 * LTOT + kt * 32 + vc1, (u16*)Vs + e1);
    __syncthreads();

    f32x4 s[2] = {};
#pragma unroll
    for (int sb = 0; sb < 2; ++sb)
#pragma unroll
      for (int c = 0; c < 4; ++c) {
        bf16x8 kf = __builtin_bit_cast(bf16x8, *(const u16x8*)&Ks[(sb * 16 + lr) * 128 + c * 32 + lk]);
        s[sb] = __builtin_amdgcn_mfma_f32_16x16x32_bf16(qf[c], kf, s[sb], 0, 0, 0);
      }
#pragma unroll
    for (int sb = 0; sb < 2; ++sb)
#pragma unroll
      for (int j = 0; j < 4; ++j) s[sb][j] *= scale;

#pragma unroll
    for (int j = 0; j < 4; ++j) {
      float mt = fmaxf(s[0][j], s[1][j]);
#pragma unroll
      for (int off = 1; off < 16; off <<= 1) mt = fmaxf(mt, __shfl_xor(mt, off, 64));
      float mnew = fmaxf(mrun[j], mt);
      float f = __expf(mrun[j] - mnew);
      float p0 = __expf(s[0][j] - mnew), p1 = __expf(s[1][j] - mnew);
      float ps = p0 + p1;
#pragma unroll
      for (int off = 1; off < 16; off <<= 1) ps += __shfl_xor(ps, off, 64);
      lrun[j] = lrun[j] * f + ps;
      mrun[j] = mnew;
#pragma unroll
      for (int nb = 0; nb < 8; ++nb) o[nb][j] *= f;
      int prow = (l >> 4) * 4 + j;
      Ps[w][prow * 32 + lr] = f2b(p0);
      Ps[w][prow * 32 + 16 + lr] = f2b(p1);
    }
    __syncthreads();
    bf16x8 pa = __builtin_bit_cast(bf16x8, *(const u16x8*)&Ps[w][lr * 32 + lk]);
#pragma unroll
    for (int nb = 0; nb < 8; ++nb) {
      bf16x8 vf = __builtin_bit_cast(bf16x8, *(const u16x8*)&Vs[(nb * 16 + lr) * 32 + lk]);
      o[nb] = __builtin_amdgcn_mfma_f32_16x16x32_bf16(pa, vf, o[nb], 0, 0, 0);
    }
  }

  int b = bh / HEADS, h = bh % HEADS;
#pragma unroll
  for (int j = 0; j < 4; ++j) {
    float inv = 1.0f / lrun[j];
    size_t row = (size_t)b * LTOT + q0 + (l >> 4) * 4 + j;
#pragma unroll
    for (int nb = 0; nb < 8; ++nb) {
      int col = h * HD + nb * 16 + lr;
      A2[row * A2W + col] = f2b(o[nb][j] * inv);
    }
  }
}

// ---------- launch ----------
extern "C" void kernel_launch(void* const* d_in, const int* in_sizes, int n_in,
                              void* d_out, int out_size, void* d_ws, size_t ws_size,
                              hipStream_t stream) {
  const void* x    = d_in[0];
  const void* vec  = d_in[1];
  const void* w1   = d_in[2];
  const void* b1   = d_in[3];
  const void* w2   = d_in[4];
  const void* b2   = d_in[5];
  const void* wmod = d_in[6];
  const void* bmod = d_in[7];
  const void* qg   = d_in[8];
  const void* kg   = d_in[9];
  const void* fcos = d_in[10];
  const void* fsin = d_in[11];

  char* p = (char*)d_ws;
  int* dflag  = (int*)p; p += 256;
  float* sv   = (float*)p; p += 32768;
  float* mod  = (float*)p; p += 131072;
  float* modp = (float*)p; p += 8 * 2 * QKVW * 4;
  u16* xmod = (u16*)p; p += (size_t)NROWS * HIDDEN * 2;
  u16* w1t  = (u16*)p; p += (size_t)N1 * HIDDEN * 2;      // reused as w2t
  u16* Qb   = (u16*)p; p += (size_t)48 * LTOT * HD * 2;
  u16* Kb   = (u16*)p; p += (size_t)48 * LTOT * HD * 2;
  u16* Vb   = (u16*)p; p += (size_t)48 * LTOT * HD * 2;
  u16* Vt   = (u16*)p; p += (size_t)48 * LTOT * HD * 2;
  u16* A2   = (u16*)p; p += (size_t)NROWS * A2W * 2;
  u16* w2t  = w1t;

  detect_kernel<<<1, 64, 0, stream>>>((const u16*)fcos, dflag);
  silu_kernel<<<24, 256, 0, stream>>>(vec, sv, dflag);
  modmul<<<dim3(36, 8), 256, 0, stream>>>(wmod, sv, modp, dflag);
  modred<<<36, 256, 0, stream>>>(modp, bmod, mod, dflag);
  ln_mod_kernel<<<NROWS, 256, 0, stream>>>(x, mod, xmod, dflag);
  transpose_cvt<<<dim3(N1 / 32, HIDDEN / 32), 256, 0, stream>>>(w1, w1t, HIDDEN, N1, dflag);
  gemm1_8ph<<<(N1 / 256) * (NROWS / 256), 512, 0, stream>>>(xmod, w1t, b1,
                                                            Qb, Kb, Vb, A2, dflag);
  rms_rope<<<48 * LTOT / 4, 256, 0, stream>>>(Qb, Kb, qg, kg, fcos, fsin, dflag);
  transpose_bf16<<<dim3(HD / 32, LTOT / 32, 48), 256, 0, stream>>>(Vb, Vt, LTOT, HD,
                                                                   (size_t)LTOT * HD, (size_t)LTOT * HD);
  attn_kernel<<<dim3(LTOT / 64, 48), 256, 0, stream>>>(Qb, Kb, Vt, A2);
  transpose_cvt<<<dim3(HIDDEN / 32, A2W / 32), 256, 0, stream>>>(w2, w2t, A2W, HIDDEN, dflag);
  gemm_bt<2><<<dim3(HIDDEN / 128, NROWS / 128), 256, 0, stream>>>(A2, w2t, A2W, b2,
                                                                  nullptr, nullptr, nullptr, nullptr,
                                                                  (float*)d_out, x, mod, dflag);
}

// Round 12
// 1476.657 us; speedup vs baseline: 1.0450x; 1.0450x over previous
//
#include <hip/hip_runtime.h>

typedef unsigned short u16;
typedef unsigned int   u32;
typedef __attribute__((ext_vector_type(2))) u16 u16x2;
typedef __attribute__((ext_vector_type(4))) u16 u16x4;
typedef __attribute__((ext_vector_type(8))) u16 u16x8;
typedef __attribute__((ext_vector_type(8))) __bf16 bf16x8;
typedef __attribute__((ext_vector_type(4))) float f32x4;

#define HIDDEN 3072
#define LTOT 1280
#define BATCH 2
#define NROWS (BATCH*LTOT)      // 2560
#define HEADS 24
#define HD 128
#define N1 21504                // 3*HIDDEN + 12288
#define QKVW 9216
#define MLPW 12288
#define A2W 15360               // HIDDEN + MLPW
#define EPSF 1e-6f

__device__ __forceinline__ float b2f(u16 u) {
  union { u32 i; float f; } v; v.i = ((u32)u) << 16; return v.f;
}
__device__ __forceinline__ u16 f2b(float f) {
  union { float f; u32 i; } v; v.f = f;
  u32 r = (v.i + 0x7FFFu + ((v.i >> 16) & 1u)) >> 16;
  return (u16)r;
}
// dual-dtype scalar load: flag=1 -> bf16, flag=0 -> f32
__device__ __forceinline__ float lde(const void* p, size_t i, int f) {
  return f ? b2f(((const u16*)p)[i]) : ((const float*)p)[i];
}
__device__ __forceinline__ void gload16(const void* g, void* l) {
  __builtin_amdgcn_global_load_lds((const __attribute__((address_space(1))) void*)g,
                                   (__attribute__((address_space(3))) void*)l, 16, 0, 0);
}
__device__ __forceinline__ bf16x8 ldf(const u16* p) {
  return __builtin_bit_cast(bf16x8, *(const u16x8*)p);
}
__device__ __forceinline__ float gelu_tanh(float x) {
  float u = 0.7978845608028654f * (x + 0.044715f * x * x * x);
  float e = __expf(2.0f * u);
  float th = 1.0f - 2.0f / (e + 1.0f);
  return 0.5f * x * (1.0f + th);
}

// ---------- dtype detect ----------
__global__ void detect_kernel(const u16* __restrict__ fcos, int* __restrict__ dflag) {
  if (threadIdx.x == 0 && blockIdx.x == 0) *dflag = (fcos[0] == 0x3F80) ? 1 : 0;
}

// ---------- small prep kernels ----------
__global__ void silu_kernel(const void* __restrict__ vec, float* __restrict__ sv,
                            const int* __restrict__ dflag) {
  int flag = *dflag;
  int i = blockIdx.x * 256 + threadIdx.x;
  if (i < BATCH * HIDDEN) { float x = lde(vec, i, flag); sv[i] = x / (1.0f + __expf(-x)); }
}

__global__ void modmul(const void* __restrict__ wmod, const float* __restrict__ sv,
                       float* __restrict__ modp, const int* __restrict__ dflag) {
  int flag = *dflag;
  int j = blockIdx.x * 256 + threadIdx.x;
  int kc = blockIdx.y;
  float a = 0.f, c = 0.f;
  int k0 = kc * 384;
  for (int k = k0; k < k0 + 384; ++k) {
    float w = lde(wmod, (size_t)k * QKVW + j, flag);
    a += sv[k] * w; c += sv[HIDDEN + k] * w;
  }
  modp[(size_t)kc * 2 * QKVW + j] = a;
  modp[(size_t)kc * 2 * QKVW + QKVW + j] = c;
}

__global__ void modred(const float* __restrict__ modp, const void* __restrict__ bmod,
                       float* __restrict__ mod, const int* __restrict__ dflag) {
  int flag = *dflag;
  int j = blockIdx.x * 256 + threadIdx.x;
  float bv = lde(bmod, j, flag);
  float a = bv, c = bv;
#pragma unroll
  for (int kc = 0; kc < 8; ++kc) {
    a += modp[(size_t)kc * 2 * QKVW + j];
    c += modp[(size_t)kc * 2 * QKVW + QKVW + j];
  }
  mod[j] = a; mod[QKVW + j] = c;
}

__global__ __launch_bounds__(256) void ln_mod_kernel(const void* __restrict__ x,
                                                     const float* __restrict__ mod,
                                                     u16* __restrict__ xmod,
                                                     const int* __restrict__ dflag) {
  int flag = *dflag;
  int row = blockIdx.x;
  int b = row / LTOT;
  int t = threadIdx.x, w = t >> 6, l = t & 63;
  float v[12], sum = 0.0f, sq = 0.0f;
  if (flag) {
    const u16* xr = (const u16*)x + (size_t)row * HIDDEN;
#pragma unroll
    for (int p = 0; p < 3; ++p) {
      u16x4 u = *(const u16x4*)&xr[p * 1024 + t * 4];
#pragma unroll
      for (int i = 0; i < 4; ++i) { float f = b2f(u[i]); v[p * 4 + i] = f; sum += f; sq += f * f; }
    }
  } else {
    const float* xr = (const float*)x + (size_t)row * HIDDEN;
#pragma unroll
    for (int p = 0; p < 3; ++p) {
      f32x4 u = *(const f32x4*)&xr[p * 1024 + t * 4];
#pragma unroll
      for (int i = 0; i < 4; ++i) { float f = u[i]; v[p * 4 + i] = f; sum += f; sq += f * f; }
    }
  }
#pragma unroll
  for (int off = 1; off < 64; off <<= 1) { sum += __shfl_xor(sum, off, 64); sq += __shfl_xor(sq, off, 64); }
  __shared__ float red[2][4];
  if (l == 0) { red[0][w] = sum; red[1][w] = sq; }
  __syncthreads();
  sum = red[0][0] + red[0][1] + red[0][2] + red[0][3];
  sq  = red[1][0] + red[1][1] + red[1][2] + red[1][3];
  float mu = sum / (float)HIDDEN;
  float var = sq / (float)HIDDEN - mu * mu;
  float rs = rsqrtf(var + EPSF);
  const float* mb = mod + (size_t)b * QKVW;
#pragma unroll
  for (int p = 0; p < 3; ++p) {
    u16x4 o;
#pragma unroll
    for (int i = 0; i < 4; ++i) {
      int col = p * 1024 + t * 4 + i;
      float y = (v[p * 4 + i] - mu) * rs;
      o[i] = f2b(y * (1.0f + mb[HIDDEN + col]) + mb[col]);
    }
    *(u16x4*)&xmod[(size_t)row * HIDDEN + p * 1024 + t * 4] = o;
  }
}

// ---------- transpose with dtype convert ----------
__global__ void transpose_cvt(const void* __restrict__ in, u16* __restrict__ out,
                              int R, int C, const int* __restrict__ dflag) {
  int flag = *dflag;
  __shared__ u16 tile[32][33];
  int bx = blockIdx.x * 32, by = blockIdx.y * 32;
  int tx = threadIdx.x & 31, ty = threadIdx.x >> 5;
#pragma unroll
  for (int i = 0; i < 32; i += 8)
    tile[ty + i][tx] = f2b(lde(in, (size_t)(by + ty + i) * C + bx + tx, flag));
  __syncthreads();
#pragma unroll
  for (int i = 0; i < 32; i += 8) out[(size_t)(bx + ty + i) * R + by + tx] = tile[tx][ty + i];
}

// ---------- transpose bf16 ----------
__global__ void transpose_bf16(const u16* __restrict__ in, u16* __restrict__ out,
                               int R, int C, size_t ibs, size_t obs) {
  in  += (size_t)blockIdx.z * ibs;
  out += (size_t)blockIdx.z * obs;
  __shared__ u16 tile[32][33];
  int bx = blockIdx.x * 32, by = blockIdx.y * 32;
  int tx = threadIdx.x & 31, ty = threadIdx.x >> 5;
#pragma unroll
  for (int i = 0; i < 32; i += 8) tile[ty + i][tx] = in[(size_t)(by + ty + i) * C + bx + tx];
  __syncthreads();
#pragma unroll
  for (int i = 0; i < 32; i += 8) out[(size_t)(bx + ty + i) * R + by + tx] = tile[tx][ty + i];
}

// ---------- GEMM1: 256x256 tile, BK=32, TRIPLE-buffered deep pipeline ----------
// Stage tile t+2 during tile t; confirm t+1 at end of tile t -> issue-to-confirm
// lead = ~4-6 phases (vs 2 before), covering observed ~2us load latency.
// Per BK-32 tile: 2 phases {ds_read subtile; stage one A/B slice; [vmcnt]; barrier;
// lgkmcnt(0)+sched_barrier; setprio(1) 16 MFMA setprio(0); barrier}.
// Ledger: end of tile t outstanding = A,B(t+1)[4] + A,B(t+2)[4] = 8 -> vmcnt(4)
// confirms t+1. Tail: t=NT-2 -> vmcnt(0); t=NT-1 -> no wait. Prologue: stage t0,t1,t2
// (12 out) -> vmcnt(8) confirms t0. Zero-conflict chunk-XOR swizzle (proven).
__global__ __launch_bounds__(512, 2) void gemm1_p3(
    const u16* __restrict__ A, const u16* __restrict__ Bt,
    const void* __restrict__ bias,
    u16* __restrict__ Qb, u16* __restrict__ Kb, u16* __restrict__ Vb,
    u16* __restrict__ A2, const int* __restrict__ dflag) {
  __shared__ u16 As[3][256][32];
  __shared__ u16 Bs[3][256][32];
  constexpr int K = HIDDEN;
  constexpr int NT = K / 32;           // 96
  const int tid = threadIdx.x;
  const int l = tid & 63, w = tid >> 6;
  const int wr = w >> 2, wc = w & 3;   // 2 x 4 wave grid; per-wave out 128x64
  const int lr = l & 15, g = l >> 4;
  const int lk_sw = (g ^ ((lr >> 1) & 3)) * 8;   // swizzled fragment k-offset (u16)

  // XCD-aware block swizzle: 840 = 8 * 105 (bijective)
  const int orig = blockIdx.x;
  const int wgid = (orig & 7) * 105 + (orig >> 3);
  const int my = wgid / 84, nx = wgid - my * 84;
  const int bm = my * 256, bn = nx * 256;

  // staging: LDS linear (base + lane*16); global source pre-swizzled (rule #21)
  const int row_s = tid >> 2, chunk = tid & 3;
  const int c_log = chunk ^ ((row_s >> 1) & 3);
  const u16* pa = A  + (size_t)(bm + row_s) * K + c_log * 8;
  const u16* pb = Bt + (size_t)(bn + row_s) * K + c_log * 8;

  auto stage_a = [&](int buf, int t) {
    const u16* sa = pa + t * 32;
    u16* la = &As[buf][row_s][chunk * 8];
    gload16(sa,                   la);
    gload16(sa + (size_t)128 * K, la + 128 * 32);
  };
  auto stage_b = [&](int buf, int t) {
    const u16* sb = pb + t * 32;
    u16* lb = &Bs[buf][row_s][chunk * 8];
    gload16(sb,                   lb);
    gload16(sb + (size_t)128 * K, lb + 128 * 32);
  };

  f32x4 acc[8][4] = {};

  // prologue: tiles 0,1,2 staged (12 outstanding); confirm tile 0
  stage_a(0, 0); stage_b(0, 0);
  stage_a(1, 1); stage_b(1, 1);
  stage_a(2, 2); stage_b(2, 2);
  asm volatile("s_waitcnt vmcnt(8)" ::: "memory");
  __builtin_amdgcn_s_barrier();

  bf16x8 af[4], bfr[4];
  for (int t = 0; t < NT; ++t) {
    const int buf = t % 3;
    const int buf2 = (t + 2) % 3;      // freed by tile t-1; receives tile t+2
    const bool pre = (t + 2 < NT);

    // ---- PH_a: rows 0-3
#pragma unroll
    for (int fc = 0; fc < 4; ++fc) bfr[fc] = ldf(&Bs[buf][wc * 64 + fc * 16 + lr][lk_sw]);
#pragma unroll
    for (int j = 0; j < 4; ++j) af[j] = ldf(&As[buf][wr * 128 + j * 16 + lr][lk_sw]);
    if (pre) stage_a(buf2, t + 2);
    __builtin_amdgcn_s_barrier();
    asm volatile("s_waitcnt lgkmcnt(0)" ::: "memory");
    __builtin_amdgcn_sched_barrier(0);
    __builtin_amdgcn_s_setprio(1);
#pragma unroll
    for (int j = 0; j < 4; ++j)
#pragma unroll
      for (int fc = 0; fc < 4; ++fc)
        acc[j][fc] = __builtin_amdgcn_mfma_f32_16x16x32_bf16(af[j], bfr[fc], acc[j][fc], 0, 0, 0);
    __builtin_amdgcn_s_setprio(0);
    __builtin_amdgcn_s_barrier();

    // ---- PH_b: rows 4-7 (bfr reused)
#pragma unroll
    for (int j = 0; j < 4; ++j) af[j] = ldf(&As[buf][wr * 128 + (4 + j) * 16 + lr][lk_sw]);
    if (pre) {
      stage_b(buf2, t + 2);
      asm volatile("s_waitcnt vmcnt(4)" ::: "memory");   // confirms tile t+1
    } else if (t + 1 < NT) {
      asm volatile("s_waitcnt vmcnt(0)" ::: "memory");   // confirms last tile
    }
    __builtin_amdgcn_s_barrier();
    asm volatile("s_waitcnt lgkmcnt(0)" ::: "memory");
    __builtin_amdgcn_sched_barrier(0);
    __builtin_amdgcn_s_setprio(1);
#pragma unroll
    for (int j = 0; j < 4; ++j)
#pragma unroll
      for (int fc = 0; fc < 4; ++fc)
        acc[4 + j][fc] = __builtin_amdgcn_mfma_f32_16x16x32_bf16(af[j], bfr[fc], acc[4 + j][fc], 0, 0, 0);
    __builtin_amdgcn_s_setprio(0);
    __builtin_amdgcn_s_barrier();
  }

  // epilogue (unchanged, proven)
  const int flag = *dflag;
#pragma unroll
  for (int fr = 0; fr < 8; ++fr) {
#pragma unroll
    for (int fc = 0; fc < 4; ++fc) {
      int colg = bn + wc * 64 + fc * 16 + lr;
      float bv = lde(bias, colg, flag);
#pragma unroll
      for (int r = 0; r < 4; ++r) {
        int rowg = bm + wr * 128 + fr * 16 + g * 4 + r;
        float v = acc[fr][fc][r] + bv;
        if (colg < QKVW) {
          int which = colg / HIDDEN;
          int hd = colg - which * HIDDEN;
          int h = hd >> 7, d = hd & 127;
          int b2 = rowg / LTOT, pos = rowg - b2 * LTOT;
          u16* dst = (which == 0) ? Qb : ((which == 1) ? Kb : Vb);
          dst[(((size_t)(b2 * HEADS + h)) * LTOT + pos) * HD + d] = f2b(v);
        } else {
          A2[(size_t)rowg * A2W + HIDDEN + (colg - QKVW)] = f2b(gelu_tanh(v));
        }
      }
    }
  }
}

// ---------- GEMM (m97 structure, kept for GEMM2) ----------
template <int MODE>
__global__ __launch_bounds__(256) void gemm_bt(
    const u16* __restrict__ A, const u16* __restrict__ Bt, int K,
    const void* __restrict__ bias,
    u16* __restrict__ out0, u16* __restrict__ out1, u16* __restrict__ out2,
    u16* __restrict__ out3, float* __restrict__ outf,
    const void* __restrict__ xin, const float* __restrict__ mod,
    const int* __restrict__ dflag) {
  __shared__ u16 As[128 * 32];
  __shared__ u16 Bs[128 * 32];
  const int flag = *dflag;
  const int t = threadIdx.x;
  const int bn = blockIdx.x * 128;
  const int bm = blockIdx.y * 128;
  const int w = t >> 6, l = t & 63;
  const int wr = (w >> 1) * 64, wc = (w & 1) * 64;
  const int lr = l & 15, lk = (l >> 4) * 8;
  f32x4 acc[4][4] = {};
  const size_t a_base = (size_t)bm * K;
  const size_t b_base = (size_t)bn * K;
  const int e0 = t * 8, e1 = e0 + 2048;
  const int r0 = e0 >> 5, c0 = e0 & 31;
  const int r1 = e1 >> 5, c1 = e1 & 31;
  const int nk = K / 32;
  for (int kt = 0; kt < nk; ++kt) {
    const int k0 = kt * 32;
    __syncthreads();
    gload16(A + a_base + (size_t)r0 * K + k0 + c0, (u16*)As + e0);
    gload16(A + a_base + (size_t)r1 * K + k0 + c1, (u16*)As + e1);
    gload16(Bt + b_base + (size_t)r0 * K + k0 + c0, (u16*)Bs + e0);
    gload16(Bt + b_base + (size_t)r1 * K + k0 + c1, (u16*)Bs + e1);
    __syncthreads();
    bf16x8 af[4], bfr[4];
#pragma unroll
    for (int i = 0; i < 4; ++i) {
      af[i]  = __builtin_bit_cast(bf16x8, *(const u16x8*)&As[(wr + i * 16 + lr) * 32 + lk]);
      bfr[i] = __builtin_bit_cast(bf16x8, *(const u16x8*)&Bs[(wc + i * 16 + lr) * 32 + lk]);
    }
#pragma unroll
    for (int i = 0; i < 4; ++i)
#pragma unroll
      for (int j = 0; j < 4; ++j)
        acc[i][j] = __builtin_amdgcn_mfma_f32_16x16x32_bf16(af[i], bfr[j], acc[i][j], 0, 0, 0);
  }
#pragma unroll
  for (int i = 0; i < 4; ++i) {
#pragma unroll
    for (int j = 0; j < 4; ++j) {
      int colg = bn + wc + j * 16 + lr;
      float bv = lde(bias, colg, flag);
#pragma unroll
      for (int r = 0; r < 4; ++r) {
        int rowg = bm + wr + i * 16 + (l >> 4) * 4 + r;
        float v = acc[i][j][r] + bv;
        if (MODE == 1) {
          // unused
        } else {
          int b = rowg / LTOT;
          float gg = mod[(size_t)b * QKVW + 2 * HIDDEN + colg];
          float xv = lde(xin, (size_t)rowg * HIDDEN + colg, flag);
          outf[(size_t)rowg * HIDDEN + colg] = xv + v * gg;
        }
      }
    }
  }
}

// ---------- in-place RMS norm + RoPE ----------
__global__ __launch_bounds__(256) void rms_rope(
    u16* __restrict__ Qb, u16* __restrict__ Kb,
    const void* __restrict__ qg, const void* __restrict__ kg,
    const void* __restrict__ fcos, const void* __restrict__ fsin,
    const int* __restrict__ dflag) {
  int flag = *dflag;
  int w = threadIdx.x >> 6, l = threadIdx.x & 63;
  int rid = blockIdx.x * 4 + w;
  int pos = rid % LTOT;
  int d0 = 2 * l;
  size_t off = (size_t)rid * HD + d0;
  u16x2 qu = *(const u16x2*)&Qb[off];
  u16x2 ku = *(const u16x2*)&Kb[off];
  float q0 = b2f(qu[0]), q1 = b2f(qu[1]);
  float k0 = b2f(ku[0]), k1 = b2f(ku[1]);
  float sq = q0 * q0 + q1 * q1, sk = k0 * k0 + k1 * k1;
#pragma unroll
  for (int o = 1; o < 64; o <<= 1) { sq += __shfl_xor(sq, o, 64); sk += __shfl_xor(sk, o, 64); }
  float rq = rsqrtf(sq / 128.0f + EPSF), rk = rsqrtf(sk / 128.0f + EPSF);
  q0 *= rq * lde(qg, d0, flag); q1 *= rq * lde(qg, d0 + 1, flag);
  k0 *= rk * lde(kg, d0, flag); k1 *= rk * lde(kg, d0 + 1, flag);
  if (pos < 1024) {
    float cc = lde(fcos, (size_t)pos * HD + d0, flag);
    float ss = lde(fsin, (size_t)pos * HD + d0, flag);
    float nq0 = q0 * cc - q1 * ss, nq1 = q1 * cc + q0 * ss;
    float nk0 = k0 * cc - k1 * ss, nk1 = k1 * cc + k0 * ss;
    q0 = nq0; q1 = nq1; k0 = nk0; k1 = nk1;
  }
  u16x2 qo; qo[0] = f2b(q0); qo[1] = f2b(q1);
  u16x2 ko; ko[0] = f2b(k0); ko[1] = f2b(k1);
  *(u16x2*)&Qb[off] = qo;
  *(u16x2*)&Kb[off] = ko;
}

// ---------- flash attention (MFMA, proven round 5) ----------
__global__ __launch_bounds__(256) void attn_kernel(
    const u16* __restrict__ Qb, const u16* __restrict__ Kb, const u16* __restrict__ Vt,
    u16* __restrict__ A2) {
  __shared__ u16 Ks[32 * 128];
  __shared__ u16 Vs[128 * 32];
  __shared__ u16 Ps[4][512];
  int t = threadIdx.x, w = t >> 6, l = t & 63;
  int bh = blockIdx.y;
  int q0 = blockIdx.x * 64 + w * 16;
  size_t base = (size_t)bh * LTOT * HD;
  int lr = l & 15, lk = (l >> 4) * 8;
  const float scale = 0.08838834764831845f;

  bf16x8 qf[4];
#pragma unroll
  for (int c = 0; c < 4; ++c)
    qf[c] = __builtin_bit_cast(bf16x8, *(const u16x8*)&Qb[base + (size_t)(q0 + lr) * HD + c * 32 + lk]);

  f32x4 o[8] = {};
  float mrun[4] = {-1e30f, -1e30f, -1e30f, -1e30f};
  float lrun[4] = {0.f, 0.f, 0.f, 0.f};

  const int e0 = t * 8, e1 = e0 + 2048;
  const int vd0 = e0 >> 5, vc0 = e0 & 31;
  const int vd1 = e1 >> 5, vc1 = e1 & 31;

  for (int kt = 0; kt < LTOT / 32; ++kt) {
    __syncthreads();
    gload16(Kb + base + (size_t)kt * 32 * HD + e0, (u16*)Ks + e0);
    gload16(Kb + base + (size_t)kt * 32 * HD + e1, (u16*)Ks + e1);
    gload16(Vt + base + (size_t)vd0 * LTOT + kt * 32 + vc0, (u16*)Vs + e0);
    gload16(Vt + base + (size_t)vd1 * LTOT + kt * 32 + vc1, (u16*)Vs + e1);
    __syncthreads();

    f32x4 s[2] = {};
#pragma unroll
    for (int sb = 0; sb < 2; ++sb)
#pragma unroll
      for (int c = 0; c < 4; ++c) {
        bf16x8 kf = __builtin_bit_cast(bf16x8, *(const u16x8*)&Ks[(sb * 16 + lr) * 128 + c * 32 + lk]);
        s[sb] = __builtin_amdgcn_mfma_f32_16x16x32_bf16(qf[c], kf, s[sb], 0, 0, 0);
      }
#pragma unroll
    for (int sb = 0; sb < 2; ++sb)
#pragma unroll
      for (int j = 0; j < 4; ++j) s[sb][j] *= scale;

#pragma unroll
    for (int j = 0; j < 4; ++j) {
      float mt = fmaxf(s[0][j], s[1][j]);
#pragma unroll
      for (int off = 1; off < 16; off <<= 1) mt = fmaxf(mt, __shfl_xor(mt, off, 64));
      float mnew = fmaxf(mrun[j], mt);
      float f = __expf(mrun[j] - mnew);
      float p0 = __expf(s[0][j] - mnew), p1 = __expf(s[1][j] - mnew);
      float ps = p0 + p1;
#pragma unroll
      for (int off = 1; off < 16; off <<= 1) ps += __shfl_xor(ps, off, 64);
      lrun[j] = lrun[j] * f + ps;
      mrun[j] = mnew;
#pragma unroll
      for (int nb = 0; nb < 8; ++nb) o[nb][j] *= f;
      int prow = (l >> 4) * 4 + j;
      Ps[w][prow * 32 + lr] = f2b(p0);
      Ps[w][prow * 32 + 16 + lr] = f2b(p1);
    }
    __syncthreads();
    bf16x8 pa = __builtin_bit_cast(bf16x8, *(const u16x8*)&Ps[w][lr * 32 + lk]);
#pragma unroll
    for (int nb = 0; nb < 8; ++nb) {
      bf16x8 vf = __builtin_bit_cast(bf16x8, *(const u16x8*)&Vs[(nb * 16 + lr) * 32 + lk]);
      o[nb] = __builtin_amdgcn_mfma_f32_16x16x32_bf16(pa, vf, o[nb], 0, 0, 0);
    }
  }

  int b = bh / HEADS, h = bh % HEADS;
#pragma unroll
  for (int j = 0; j < 4; ++j) {
    float inv = 1.0f / lrun[j];
    size_t row = (size_t)b * LTOT + q0 + (l >> 4) * 4 + j;
#pragma unroll
    for (int nb = 0; nb < 8; ++nb) {
      int col = h * HD + nb * 16 + lr;
      A2[row * A2W + col] = f2b(o[nb][j] * inv);
    }
  }
}

// ---------- launch ----------
extern "C" void kernel_launch(void* const* d_in, const int* in_sizes, int n_in,
                              void* d_out, int out_size, void* d_ws, size_t ws_size,
                              hipStream_t stream) {
  const void* x    = d_in[0];
  const void* vec  = d_in[1];
  const void* w1   = d_in[2];
  const void* b1   = d_in[3];
  const void* w2   = d_in[4];
  const void* b2   = d_in[5];
  const void* wmod = d_in[6];
  const void* bmod = d_in[7];
  const void* qg   = d_in[8];
  const void* kg   = d_in[9];
  const void* fcos = d_in[10];
  const void* fsin = d_in[11];

  char* p = (char*)d_ws;
  int* dflag  = (int*)p; p += 256;
  float* sv   = (float*)p; p += 32768;
  float* mod  = (float*)p; p += 131072;
  float* modp = (float*)p; p += 8 * 2 * QKVW * 4;
  u16* xmod = (u16*)p; p += (size_t)NROWS * HIDDEN * 2;
  u16* w1t  = (u16*)p; p += (size_t)N1 * HIDDEN * 2;      // reused as w2t
  u16* Qb   = (u16*)p; p += (size_t)48 * LTOT * HD * 2;
  u16* Kb   = (u16*)p; p += (size_t)48 * LTOT * HD * 2;
  u16* Vb   = (u16*)p; p += (size_t)48 * LTOT * HD * 2;
  u16* Vt   = (u16*)p; p += (size_t)48 * LTOT * HD * 2;
  u16* A2   = (u16*)p; p += (size_t)NROWS * A2W * 2;
  u16* w2t  = w1t;

  detect_kernel<<<1, 64, 0, stream>>>((const u16*)fcos, dflag);
  silu_kernel<<<24, 256, 0, stream>>>(vec, sv, dflag);
  modmul<<<dim3(36, 8), 256, 0, stream>>>(wmod, sv, modp, dflag);
  modred<<<36, 256, 0, stream>>>(modp, bmod, mod, dflag);
  ln_mod_kernel<<<NROWS, 256, 0, stream>>>(x, mod, xmod, dflag);
  transpose_cvt<<<dim3(N1 / 32, HIDDEN / 32), 256, 0, stream>>>(w1, w1t, HIDDEN, N1, dflag);
  gemm1_p3<<<(N1 / 256) * (NROWS / 256), 512, 0, stream>>>(xmod, w1t, b1,
                                                           Qb, Kb, Vb, A2, dflag);
  rms_rope<<<48 * LTOT / 4, 256, 0, stream>>>(Qb, Kb, qg, kg, fcos, fsin, dflag);
  transpose_bf16<<<dim3(HD / 32, LTOT / 32, 48), 256, 0, stream>>>(Vb, Vt, LTOT, HD,
                                                                   (size_t)LTOT * HD, (size_t)LTOT * HD);
  attn_kernel<<<dim3(LTOT / 64, 48), 256, 0, stream>>>(Qb, Kb, Vt, A2);
  transpose_cvt<<<dim3(HIDDEN / 32, A2W / 32), 256, 0, stream>>>(w2, w2t, A2W, HIDDEN, dflag);
  gemm_bt<2><<<dim3(HIDDEN / 128, NROWS / 128), 256, 0, stream>>>(A2, w2t, A2W, b2,
                                                                  nullptr, nullptr, nullptr, nullptr,
                                                                  (float*)d_out, x, mod, dflag);
}

// Round 13
// 1317.250 us; speedup vs baseline: 1.1715x; 1.1210x over previous
//
#include <hip/hip_runtime.h>

typedef unsigned short u16;
typedef unsigned int   u32;
typedef __attribute__((ext_vector_type(2))) u16 u16x2;
typedef __attribute__((ext_vector_type(4))) u16 u16x4;
typedef __attribute__((ext_vector_type(8))) u16 u16x8;
typedef __attribute__((ext_vector_type(8))) __bf16 bf16x8;
typedef __attribute__((ext_vector_type(4))) float f32x4;

#define HIDDEN 3072
#define LTOT 1280
#define BATCH 2
#define NROWS (BATCH*LTOT)      // 2560
#define HEADS 24
#define HD 128
#define N1 21504                // 3*HIDDEN + 12288
#define QKVW 9216
#define MLPW 12288
#define A2W 15360               // HIDDEN + MLPW
#define EPSF 1e-6f

__device__ __forceinline__ float b2f(u16 u) {
  union { u32 i; float f; } v; v.i = ((u32)u) << 16; return v.f;
}
__device__ __forceinline__ u16 f2b(float f) {
  union { float f; u32 i; } v; v.f = f;
  u32 r = (v.i + 0x7FFFu + ((v.i >> 16) & 1u)) >> 16;
  return (u16)r;
}
// dual-dtype scalar load: flag=1 -> bf16, flag=0 -> f32
__device__ __forceinline__ float lde(const void* p, size_t i, int f) {
  return f ? b2f(((const u16*)p)[i]) : ((const float*)p)[i];
}
__device__ __forceinline__ void gload16(const void* g, void* l) {
  __builtin_amdgcn_global_load_lds((const __attribute__((address_space(1))) void*)g,
                                   (__attribute__((address_space(3))) void*)l, 16, 0, 0);
}
__device__ __forceinline__ bf16x8 ldf(const u16* p) {
  return __builtin_bit_cast(bf16x8, *(const u16x8*)p);
}
__device__ __forceinline__ float gelu_tanh(float x) {
  float u = 0.7978845608028654f * (x + 0.044715f * x * x * x);
  float e = __expf(2.0f * u);
  float th = 1.0f - 2.0f / (e + 1.0f);
  return 0.5f * x * (1.0f + th);
}

// ---------- dtype detect ----------
__global__ void detect_kernel(const u16* __restrict__ fcos, int* __restrict__ dflag) {
  if (threadIdx.x == 0 && blockIdx.x == 0) *dflag = (fcos[0] == 0x3F80) ? 1 : 0;
}

// ---------- small prep kernels ----------
__global__ void silu_kernel(const void* __restrict__ vec, float* __restrict__ sv,
                            const int* __restrict__ dflag) {
  int flag = *dflag;
  int i = blockIdx.x * 256 + threadIdx.x;
  if (i < BATCH * HIDDEN) { float x = lde(vec, i, flag); sv[i] = x / (1.0f + __expf(-x)); }
}

__global__ void modmul(const void* __restrict__ wmod, const float* __restrict__ sv,
                       float* __restrict__ modp, const int* __restrict__ dflag) {
  int flag = *dflag;
  int j = blockIdx.x * 256 + threadIdx.x;
  int kc = blockIdx.y;
  float a = 0.f, c = 0.f;
  int k0 = kc * 384;
  for (int k = k0; k < k0 + 384; ++k) {
    float w = lde(wmod, (size_t)k * QKVW + j, flag);
    a += sv[k] * w; c += sv[HIDDEN + k] * w;
  }
  modp[(size_t)kc * 2 * QKVW + j] = a;
  modp[(size_t)kc * 2 * QKVW + QKVW + j] = c;
}

__global__ void modred(const float* __restrict__ modp, const void* __restrict__ bmod,
                       float* __restrict__ mod, const int* __restrict__ dflag) {
  int flag = *dflag;
  int j = blockIdx.x * 256 + threadIdx.x;
  float bv = lde(bmod, j, flag);
  float a = bv, c = bv;
#pragma unroll
  for (int kc = 0; kc < 8; ++kc) {
    a += modp[(size_t)kc * 2 * QKVW + j];
    c += modp[(size_t)kc * 2 * QKVW + QKVW + j];
  }
  mod[j] = a; mod[QKVW + j] = c;
}

__global__ __launch_bounds__(256) void ln_mod_kernel(const void* __restrict__ x,
                                                     const float* __restrict__ mod,
                                                     u16* __restrict__ xmod,
                                                     const int* __restrict__ dflag) {
  int flag = *dflag;
  int row = blockIdx.x;
  int b = row / LTOT;
  int t = threadIdx.x, w = t >> 6, l = t & 63;
  float v[12], sum = 0.0f, sq = 0.0f;
  if (flag) {
    const u16* xr = (const u16*)x + (size_t)row * HIDDEN;
#pragma unroll
    for (int p = 0; p < 3; ++p) {
      u16x4 u = *(const u16x4*)&xr[p * 1024 + t * 4];
#pragma unroll
      for (int i = 0; i < 4; ++i) { float f = b2f(u[i]); v[p * 4 + i] = f; sum += f; sq += f * f; }
    }
  } else {
    const float* xr = (const float*)x + (size_t)row * HIDDEN;
#pragma unroll
    for (int p = 0; p < 3; ++p) {
      f32x4 u = *(const f32x4*)&xr[p * 1024 + t * 4];
#pragma unroll
      for (int i = 0; i < 4; ++i) { float f = u[i]; v[p * 4 + i] = f; sum += f; sq += f * f; }
    }
  }
#pragma unroll
  for (int off = 1; off < 64; off <<= 1) { sum += __shfl_xor(sum, off, 64); sq += __shfl_xor(sq, off, 64); }
  __shared__ float red[2][4];
  if (l == 0) { red[0][w] = sum; red[1][w] = sq; }
  __syncthreads();
  sum = red[0][0] + red[0][1] + red[0][2] + red[0][3];
  sq  = red[1][0] + red[1][1] + red[1][2] + red[1][3];
  float mu = sum / (float)HIDDEN;
  float var = sq / (float)HIDDEN - mu * mu;
  float rs = rsqrtf(var + EPSF);
  const float* mb = mod + (size_t)b * QKVW;
#pragma unroll
  for (int p = 0; p < 3; ++p) {
    u16x4 o;
#pragma unroll
    for (int i = 0; i < 4; ++i) {
      int col = p * 1024 + t * 4 + i;
      float y = (v[p * 4 + i] - mu) * rs;
      o[i] = f2b(y * (1.0f + mb[HIDDEN + col]) + mb[col]);
    }
    *(u16x4*)&xmod[(size_t)row * HIDDEN + p * 1024 + t * 4] = o;
  }
}

// ---------- transpose with dtype convert ----------
__global__ void transpose_cvt(const void* __restrict__ in, u16* __restrict__ out,
                              int R, int C, const int* __restrict__ dflag) {
  int flag = *dflag;
  __shared__ u16 tile[32][33];
  int bx = blockIdx.x * 32, by = blockIdx.y * 32;
  int tx = threadIdx.x & 31, ty = threadIdx.x >> 5;
#pragma unroll
  for (int i = 0; i < 32; i += 8)
    tile[ty + i][tx] = f2b(lde(in, (size_t)(by + ty + i) * C + bx + tx, flag));
  __syncthreads();
#pragma unroll
  for (int i = 0; i < 32; i += 8) out[(size_t)(bx + ty + i) * R + by + tx] = tile[tx][ty + i];
}

// ---------- transpose bf16 ----------
__global__ void transpose_bf16(const u16* __restrict__ in, u16* __restrict__ out,
                               int R, int C, size_t ibs, size_t obs) {
  in  += (size_t)blockIdx.z * ibs;
  out += (size_t)blockIdx.z * obs;
  __shared__ u16 tile[32][33];
  int bx = blockIdx.x * 32, by = blockIdx.y * 32;
  int tx = threadIdx.x & 31, ty = threadIdx.x >> 5;
#pragma unroll
  for (int i = 0; i < 32; i += 8) tile[ty + i][tx] = in[(size_t)(by + ty + i) * C + bx + tx];
  __syncthreads();
#pragma unroll
  for (int i = 0; i < 32; i += 8) out[(size_t)(bx + ty + i) * R + by + tx] = tile[tx][ty + i];
}

// ---------- GEMM1: 256x256 tile, BK=32, triple-buffered deep pipeline (proven r12) ----------
__global__ __launch_bounds__(512, 2) void gemm1_p3(
    const u16* __restrict__ A, const u16* __restrict__ Bt,
    const void* __restrict__ bias,
    u16* __restrict__ Qb, u16* __restrict__ Kb, u16* __restrict__ Vb,
    u16* __restrict__ A2, const int* __restrict__ dflag) {
  __shared__ u16 As[3][256][32];
  __shared__ u16 Bs[3][256][32];
  constexpr int K = HIDDEN;
  constexpr int NT = K / 32;           // 96
  const int tid = threadIdx.x;
  const int l = tid & 63, w = tid >> 6;
  const int wr = w >> 2, wc = w & 3;
  const int lr = l & 15, g = l >> 4;
  const int lk_sw = (g ^ ((lr >> 1) & 3)) * 8;

  const int orig = blockIdx.x;
  const int wgid = (orig & 7) * 105 + (orig >> 3);   // 840 = 8*105 bijective
  const int my = wgid / 84, nx = wgid - my * 84;
  const int bm = my * 256, bn = nx * 256;

  const int row_s = tid >> 2, chunk = tid & 3;
  const int c_log = chunk ^ ((row_s >> 1) & 3);
  const u16* pa = A  + (size_t)(bm + row_s) * K + c_log * 8;
  const u16* pb = Bt + (size_t)(bn + row_s) * K + c_log * 8;

  auto stage_a = [&](int buf, int t) {
    const u16* sa = pa + t * 32;
    u16* la = &As[buf][row_s][chunk * 8];
    gload16(sa,                   la);
    gload16(sa + (size_t)128 * K, la + 128 * 32);
  };
  auto stage_b = [&](int buf, int t) {
    const u16* sb = pb + t * 32;
    u16* lb = &Bs[buf][row_s][chunk * 8];
    gload16(sb,                   lb);
    gload16(sb + (size_t)128 * K, lb + 128 * 32);
  };

  f32x4 acc[8][4] = {};

  // prologue: tiles 0,1 staged (8 outstanding); confirm tile 0
  stage_a(0, 0); stage_b(0, 0);
  stage_a(1, 1); stage_b(1, 1);
  asm volatile("s_waitcnt vmcnt(4)" ::: "memory");
  __builtin_amdgcn_s_barrier();

  bf16x8 af[4], bfr[4];
  for (int t = 0; t < NT; ++t) {
    const int buf = t % 3;
    const int buf2 = (t + 2) % 3;
    const bool pre = (t + 2 < NT);

    // ---- PH_a: rows 0-3
#pragma unroll
    for (int fc = 0; fc < 4; ++fc) bfr[fc] = ldf(&Bs[buf][wc * 64 + fc * 16 + lr][lk_sw]);
#pragma unroll
    for (int j = 0; j < 4; ++j) af[j] = ldf(&As[buf][wr * 128 + j * 16 + lr][lk_sw]);
    if (pre) stage_a(buf2, t + 2);
    __builtin_amdgcn_s_barrier();
    asm volatile("s_waitcnt lgkmcnt(0)" ::: "memory");
    __builtin_amdgcn_sched_barrier(0);
    __builtin_amdgcn_s_setprio(1);
#pragma unroll
    for (int j = 0; j < 4; ++j)
#pragma unroll
      for (int fc = 0; fc < 4; ++fc)
        acc[j][fc] = __builtin_amdgcn_mfma_f32_16x16x32_bf16(af[j], bfr[fc], acc[j][fc], 0, 0, 0);
    __builtin_amdgcn_s_setprio(0);
    __builtin_amdgcn_s_barrier();

    // ---- PH_b: rows 4-7 (bfr reused)
#pragma unroll
    for (int j = 0; j < 4; ++j) af[j] = ldf(&As[buf][wr * 128 + (4 + j) * 16 + lr][lk_sw]);
    if (pre) {
      stage_b(buf2, t + 2);
      asm volatile("s_waitcnt vmcnt(4)" ::: "memory");   // confirms tile t+1
    } else if (t + 1 < NT) {
      asm volatile("s_waitcnt vmcnt(0)" ::: "memory");
    }
    __builtin_amdgcn_s_barrier();
    asm volatile("s_waitcnt lgkmcnt(0)" ::: "memory");
    __builtin_amdgcn_sched_barrier(0);
    __builtin_amdgcn_s_setprio(1);
#pragma unroll
    for (int j = 0; j < 4; ++j)
#pragma unroll
      for (int fc = 0; fc < 4; ++fc)
        acc[4 + j][fc] = __builtin_amdgcn_mfma_f32_16x16x32_bf16(af[j], bfr[fc], acc[4 + j][fc], 0, 0, 0);
    __builtin_amdgcn_s_setprio(0);
    __builtin_amdgcn_s_barrier();
  }

  // epilogue (proven)
  const int flag = *dflag;
#pragma unroll
  for (int fr = 0; fr < 8; ++fr) {
#pragma unroll
    for (int fc = 0; fc < 4; ++fc) {
      int colg = bn + wc * 64 + fc * 16 + lr;
      float bv = lde(bias, colg, flag);
#pragma unroll
      for (int r = 0; r < 4; ++r) {
        int rowg = bm + wr * 128 + fr * 16 + g * 4 + r;
        float v = acc[fr][fc][r] + bv;
        if (colg < QKVW) {
          int which = colg / HIDDEN;
          int hd = colg - which * HIDDEN;
          int h = hd >> 7, d = hd & 127;
          int b2 = rowg / LTOT, pos = rowg - b2 * LTOT;
          u16* dst = (which == 0) ? Qb : ((which == 1) ? Kb : Vb);
          dst[(((size_t)(b2 * HEADS + h)) * LTOT + pos) * HD + d] = f2b(v);
        } else {
          A2[(size_t)rowg * A2W + HIDDEN + (colg - QKVW)] = f2b(gelu_tanh(v));
        }
      }
    }
  }
}

// ---------- GEMM2: same p3 pipeline, split-K=2, f32 partials ----------
// A = A2 (2560 x 15360), Bt = w2t (3072 x 15360). blockIdx.y = K-half.
// Epilogue: raw f32 partial -> psum[s][M][N]; bias/gate/residual in gemm2_reduce.
__global__ __launch_bounds__(512, 2) void gemm2_p3(
    const u16* __restrict__ A, const u16* __restrict__ Bt,
    float* __restrict__ psum) {
  __shared__ u16 As[3][256][32];
  __shared__ u16 Bs[3][256][32];
  constexpr int K = A2W;               // 15360
  constexpr int NT = 7680 / 32;        // 240 tiles per half
  const int tid = threadIdx.x;
  const int l = tid & 63, w = tid >> 6;
  const int wr = w >> 2, wc = w & 3;
  const int lr = l & 15, g = l >> 4;
  const int lk_sw = (g ^ ((lr >> 1) & 3)) * 8;

  const int s = blockIdx.y;            // K-half
  const int orig = blockIdx.x;         // 120 = 8*15 bijective
  const int wgid = (orig & 7) * 15 + (orig >> 3);
  const int my = wgid / 12, nx = wgid - my * 12;
  const int bm = my * 256, bn = nx * 256;
  const int kbase = s * 7680;

  const int row_s = tid >> 2, chunk = tid & 3;
  const int c_log = chunk ^ ((row_s >> 1) & 3);
  const u16* pa = A  + (size_t)(bm + row_s) * K + kbase + c_log * 8;
  const u16* pb = Bt + (size_t)(bn + row_s) * K + kbase + c_log * 8;

  auto stage_a = [&](int buf, int t) {
    const u16* sa = pa + t * 32;
    u16* la = &As[buf][row_s][chunk * 8];
    gload16(sa,                   la);
    gload16(sa + (size_t)128 * K, la + 128 * 32);
  };
  auto stage_b = [&](int buf, int t) {
    const u16* sb = pb + t * 32;
    u16* lb = &Bs[buf][row_s][chunk * 8];
    gload16(sb,                   lb);
    gload16(sb + (size_t)128 * K, lb + 128 * 32);
  };

  f32x4 acc[8][4] = {};

  stage_a(0, 0); stage_b(0, 0);
  stage_a(1, 1); stage_b(1, 1);
  asm volatile("s_waitcnt vmcnt(4)" ::: "memory");
  __builtin_amdgcn_s_barrier();

  bf16x8 af[4], bfr[4];
  for (int t = 0; t < NT; ++t) {
    const int buf = t % 3;
    const int buf2 = (t + 2) % 3;
    const bool pre = (t + 2 < NT);

#pragma unroll
    for (int fc = 0; fc < 4; ++fc) bfr[fc] = ldf(&Bs[buf][wc * 64 + fc * 16 + lr][lk_sw]);
#pragma unroll
    for (int j = 0; j < 4; ++j) af[j] = ldf(&As[buf][wr * 128 + j * 16 + lr][lk_sw]);
    if (pre) stage_a(buf2, t + 2);
    __builtin_amdgcn_s_barrier();
    asm volatile("s_waitcnt lgkmcnt(0)" ::: "memory");
    __builtin_amdgcn_sched_barrier(0);
    __builtin_amdgcn_s_setprio(1);
#pragma unroll
    for (int j = 0; j < 4; ++j)
#pragma unroll
      for (int fc = 0; fc < 4; ++fc)
        acc[j][fc] = __builtin_amdgcn_mfma_f32_16x16x32_bf16(af[j], bfr[fc], acc[j][fc], 0, 0, 0);
    __builtin_amdgcn_s_setprio(0);
    __builtin_amdgcn_s_barrier();

#pragma unroll
    for (int j = 0; j < 4; ++j) af[j] = ldf(&As[buf][wr * 128 + (4 + j) * 16 + lr][lk_sw]);
    if (pre) {
      stage_b(buf2, t + 2);
      asm volatile("s_waitcnt vmcnt(4)" ::: "memory");
    } else if (t + 1 < NT) {
      asm volatile("s_waitcnt vmcnt(0)" ::: "memory");
    }
    __builtin_amdgcn_s_barrier();
    asm volatile("s_waitcnt lgkmcnt(0)" ::: "memory");
    __builtin_amdgcn_sched_barrier(0);
    __builtin_amdgcn_s_setprio(1);
#pragma unroll
    for (int j = 0; j < 4; ++j)
#pragma unroll
      for (int fc = 0; fc < 4; ++fc)
        acc[4 + j][fc] = __builtin_amdgcn_mfma_f32_16x16x32_bf16(af[j], bfr[fc], acc[4 + j][fc], 0, 0, 0);
    __builtin_amdgcn_s_setprio(0);
    __builtin_amdgcn_s_barrier();
  }

  float* pout = psum + (size_t)s * NROWS * HIDDEN;
#pragma unroll
  for (int fr = 0; fr < 8; ++fr) {
#pragma unroll
    for (int fc = 0; fc < 4; ++fc) {
      int colg = bn + wc * 64 + fc * 16 + lr;
#pragma unroll
      for (int r = 0; r < 4; ++r) {
        int rowg = bm + wr * 128 + fr * 16 + g * 4 + r;
        pout[(size_t)rowg * HIDDEN + colg] = acc[fr][fc][r];
      }
    }
  }
}

// ---------- GEMM2 reduce: out = x + (p0+p1+bias)*gate (f32 out) ----------
__global__ __launch_bounds__(256) void gemm2_reduce(
    const float* __restrict__ psum, const void* __restrict__ bias,
    const float* __restrict__ mod, const void* __restrict__ xin,
    float* __restrict__ outf, const int* __restrict__ dflag) {
  int flag = *dflag;
  int col = blockIdx.x * 1024 + threadIdx.x * 4;
  int row = blockIdx.y;
  int b = row / LTOT;
  f32x4 v0 = *(const f32x4*)&psum[(size_t)row * HIDDEN + col];
  f32x4 v1 = *(const f32x4*)&psum[((size_t)NROWS + row) * HIDDEN + col];
  f32x4 o;
#pragma unroll
  for (int i = 0; i < 4; ++i) {
    float gg = mod[(size_t)b * QKVW + 2 * HIDDEN + col + i];
    float bv = lde(bias, col + i, flag);
    float xv = lde(xin, (size_t)row * HIDDEN + col + i, flag);
    o[i] = xv + (v0[i] + v1[i] + bv) * gg;
  }
  *(f32x4*)&outf[(size_t)row * HIDDEN + col] = o;
}

// ---------- in-place RMS norm + RoPE ----------
__global__ __launch_bounds__(256) void rms_rope(
    u16* __restrict__ Qb, u16* __restrict__ Kb,
    const void* __restrict__ qg, const void* __restrict__ kg,
    const void* __restrict__ fcos, const void* __restrict__ fsin,
    const int* __restrict__ dflag) {
  int flag = *dflag;
  int w = threadIdx.x >> 6, l = threadIdx.x & 63;
  int rid = blockIdx.x * 4 + w;
  int pos = rid % LTOT;
  int d0 = 2 * l;
  size_t off = (size_t)rid * HD + d0;
  u16x2 qu = *(const u16x2*)&Qb[off];
  u16x2 ku = *(const u16x2*)&Kb[off];
  float q0 = b2f(qu[0]), q1 = b2f(qu[1]);
  float k0 = b2f(ku[0]), k1 = b2f(ku[1]);
  float sq = q0 * q0 + q1 * q1, sk = k0 * k0 + k1 * k1;
#pragma unroll
  for (int o = 1; o < 64; o <<= 1) { sq += __shfl_xor(sq, o, 64); sk += __shfl_xor(sk, o, 64); }
  float rq = rsqrtf(sq / 128.0f + EPSF), rk = rsqrtf(sk / 128.0f + EPSF);
  q0 *= rq * lde(qg, d0, flag); q1 *= rq * lde(qg, d0 + 1, flag);
  k0 *= rk * lde(kg, d0, flag); k1 *= rk * lde(kg, d0 + 1, flag);
  if (pos < 1024) {
    float cc = lde(fcos, (size_t)pos * HD + d0, flag);
    float ss = lde(fsin, (size_t)pos * HD + d0, flag);
    float nq0 = q0 * cc - q1 * ss, nq1 = q1 * cc + q0 * ss;
    float nk0 = k0 * cc - k1 * ss, nk1 = k1 * cc + k0 * ss;
    q0 = nq0; q1 = nq1; k0 = nk0; k1 = nk1;
  }
  u16x2 qo; qo[0] = f2b(q0); qo[1] = f2b(q1);
  u16x2 ko; ko[0] = f2b(k0); ko[1] = f2b(k1);
  *(u16x2*)&Qb[off] = qo;
  *(u16x2*)&Kb[off] = ko;
}

// ---------- flash attention (MFMA, proven round 5) ----------
__global__ __launch_bounds__(256) void attn_kernel(
    const u16* __restrict__ Qb, const u16* __restrict__ Kb, const u16* __restrict__ Vt,
    u16* __restrict__ A2) {
  __shared__ u16 Ks[32 * 128];
  __shared__ u16 Vs[128 * 32];
  __shared__ u16 Ps[4][512];
  int t = threadIdx.x, w = t >> 6, l = t & 63;
  int bh = blockIdx.y;
  int q0 = blockIdx.x * 64 + w * 16;
  size_t base = (size_t)bh * LTOT * HD;
  int lr = l & 15, lk = (l >> 4) * 8;
  const float scale = 0.08838834764831845f;

  bf16x8 qf[4];
#pragma unroll
  for (int c = 0; c < 4; ++c)
    qf[c] = __builtin_bit_cast(bf16x8, *(const u16x8*)&Qb[base + (size_t)(q0 + lr) * HD + c * 32 + lk]);

  f32x4 o[8] = {};
  float mrun[4] = {-1e30f, -1e30f, -1e30f, -1e30f};
  float lrun[4] = {0.f, 0.f, 0.f, 0.f};

  const int e0 = t * 8, e1 = e0 + 2048;
  const int vd0 = e0 >> 5, vc0 = e0 & 31;
  const int vd1 = e1 >> 5, vc1 = e1 & 31;

  for (int kt = 0; kt < LTOT / 32; ++kt) {
    __syncthreads();
    gload16(Kb + base + (size_t)kt * 32 * HD + e0, (u16*)Ks + e0);
    gload16(Kb + base + (size_t)kt * 32 * HD + e1, (u16*)Ks + e1);
    gload16(Vt + base + (size_t)vd0 * LTOT + kt * 32 + vc0, (u16*)Vs + e0);
    gload16(Vt + base + (size_t)vd1 * LTOT + kt * 32 + vc1, (u16*)Vs + e1);
    __syncthreads();

    f32x4 s[2] = {};
#pragma unroll
    for (int sb = 0; sb < 2; ++sb)
#pragma unroll
      for (int c = 0; c < 4; ++c) {
        bf16x8 kf = __builtin_bit_cast(bf16x8, *(const u16x8*)&Ks[(sb * 16 + lr) * 128 + c * 32 + lk]);
        s[sb] = __builtin_amdgcn_mfma_f32_16x16x32_bf16(qf[c], kf, s[sb], 0, 0, 0);
      }
#pragma unroll
    for (int sb = 0; sb < 2; ++sb)
#pragma unroll
      for (int j = 0; j < 4; ++j) s[sb][j] *= scale;

#pragma unroll
    for (int j = 0; j < 4; ++j) {
      float mt = fmaxf(s[0][j], s[1][j]);
#pragma unroll
      for (int off = 1; off < 16; off <<= 1) mt = fmaxf(mt, __shfl_xor(mt, off, 64));
      float mnew = fmaxf(mrun[j], mt);
      float f = __expf(mrun[j] - mnew);
      float p0 = __expf(s[0][j] - mnew), p1 = __expf(s[1][j] - mnew);
      float ps = p0 + p1;
#pragma unroll
      for (int off = 1; off < 16; off <<= 1) ps += __shfl_xor(ps, off, 64);
      lrun[j] = lrun[j] * f + ps;
      mrun[j] = mnew;
#pragma unroll
      for (int nb = 0; nb < 8; ++nb) o[nb][j] *= f;
      int prow = (l >> 4) * 4 + j;
      Ps[w][prow * 32 + lr] = f2b(p0);
      Ps[w][prow * 32 + 16 + lr] = f2b(p1);
    }
    __syncthreads();
    bf16x8 pa = __builtin_bit_cast(bf16x8, *(const u16x8*)&Ps[w][lr * 32 + lk]);
#pragma unroll
    for (int nb = 0; nb < 8; ++nb) {
      bf16x8 vf = __builtin_bit_cast(bf16x8, *(const u16x8*)&Vs[(nb * 16 + lr) * 32 + lk]);
      o[nb] = __builtin_amdgcn_mfma_f32_16x16x32_bf16(pa, vf, o[nb], 0, 0, 0);
    }
  }

  int b = bh / HEADS, h = bh % HEADS;
#pragma unroll
  for (int j = 0; j < 4; ++j) {
    float inv = 1.0f / lrun[j];
    size_t row = (size_t)b * LTOT + q0 + (l >> 4) * 4 + j;
#pragma unroll
    for (int nb = 0; nb < 8; ++nb) {
      int col = h * HD + nb * 16 + lr;
      A2[row * A2W + col] = f2b(o[nb][j] * inv);
    }
  }
}

// ---------- launch ----------
extern "C" void kernel_launch(void* const* d_in, const int* in_sizes, int n_in,
                              void* d_out, int out_size, void* d_ws, size_t ws_size,
                              hipStream_t stream) {
  const void* x    = d_in[0];
  const void* vec  = d_in[1];
  const void* w1   = d_in[2];
  const void* b1   = d_in[3];
  const void* w2   = d_in[4];
  const void* b2   = d_in[5];
  const void* wmod = d_in[6];
  const void* bmod = d_in[7];
  const void* qg   = d_in[8];
  const void* kg   = d_in[9];
  const void* fcos = d_in[10];
  const void* fsin = d_in[11];

  char* p = (char*)d_ws;
  int* dflag  = (int*)p; p += 256;
  float* sv   = (float*)p; p += 32768;
  float* mod  = (float*)p; p += 131072;
  float* modp = (float*)p; p += 8 * 2 * QKVW * 4;
  u16* xmod = (u16*)p; p += (size_t)NROWS * HIDDEN * 2;
  u16* w1t  = (u16*)p; p += (size_t)N1 * HIDDEN * 2;      // reused as w2t
  u16* Qb   = (u16*)p; p += (size_t)48 * LTOT * HD * 2;
  u16* Kb   = (u16*)p; p += (size_t)48 * LTOT * HD * 2;
  u16* Vb   = (u16*)p; p += (size_t)48 * LTOT * HD * 2;
  u16* Vt   = (u16*)p; p += (size_t)48 * LTOT * HD * 2;
  u16* A2   = (u16*)p; p += (size_t)NROWS * A2W * 2;
  u16* w2t  = w1t;                 // w1t dead after gemm1
  float* psum = (float*)Qb;        // Qb..Vt (62.9 MB) dead after attn; psum = 2*2560*3072*4 = 62.9 MB

  detect_kernel<<<1, 64, 0, stream>>>((const u16*)fcos, dflag);
  silu_kernel<<<24, 256, 0, stream>>>(vec, sv, dflag);
  modmul<<<dim3(36, 8), 256, 0, stream>>>(wmod, sv, modp, dflag);
  modred<<<36, 256, 0, stream>>>(modp, bmod, mod, dflag);
  ln_mod_kernel<<<NROWS, 256, 0, stream>>>(x, mod, xmod, dflag);
  transpose_cvt<<<dim3(N1 / 32, HIDDEN / 32), 256, 0, stream>>>(w1, w1t, HIDDEN, N1, dflag);
  gemm1_p3<<<(N1 / 256) * (NROWS / 256), 512, 0, stream>>>(xmod, w1t, b1,
                                                           Qb, Kb, Vb, A2, dflag);
  rms_rope<<<48 * LTOT / 4, 256, 0, stream>>>(Qb, Kb, qg, kg, fcos, fsin, dflag);
  transpose_bf16<<<dim3(HD / 32, LTOT / 32, 48), 256, 0, stream>>>(Vb, Vt, LTOT, HD,
                                                                   (size_t)LTOT * HD, (size_t)LTOT * HD);
  attn_kernel<<<dim3(LTOT / 64, 48), 256, 0, stream>>>(Qb, Kb, Vt, A2);
  transpose_cvt<<<dim3(HIDDEN / 32, A2W / 32), 256, 0, stream>>>(w2, w2t, A2W, HIDDEN, dflag);
  gemm2_p3<<<dim3(120, 2), 512, 0, stream>>>(A2, w2t, psum);
  gemm2_reduce<<<dim3(3, NROWS), 256, 0, stream>>>(psum, b2, mod, x, (float*)d_out, dflag);
}